// Round 8
// baseline (466.576 us; speedup 1.0000x reference)
//
#include <hip/hip_runtime.h>

#define H 128          // hidden dim (fixed by problem)
#define CAP 64         // max edges per (rel,dst) bucket
#define BSTRIDE 392    // LDS col stride for B-half: 384 + 8 f16 -> 2-way conflicts only

typedef _Float16 f16x8 __attribute__((ext_vector_type(8)));
typedef float    f32x4 __attribute__((ext_vector_type(4)));

// ---------------- edge bucketing: one pass, reused by both layers ----------------
__global__ __launch_bounds__(256) void hist_fill(const int* __restrict__ src,
    const int* __restrict__ dst, const int* __restrict__ et,
    int* __restrict__ cnt, int* __restrict__ elist, int E, int N)
{
    int e = blockIdx.x * 256 + threadIdx.x;
    if (e >= E) return;
    int s = src[e], d = dst[e], t = et[e];
    int b = t * N + d;
    int pos = atomicAdd(&cnt[b], 1);
    if (pos < CAP) elist[(size_t)b * CAP + pos] = s;
}

// ---------------- weight prep: transpose + fp32->fp16 ----------------
__global__ __launch_bounds__(256) void prep_w(const float* __restrict__ w_in,
    const float* __restrict__ w_root, const float* __restrict__ w_rel,
    _Float16* __restrict__ wInT, _Float16* __restrict__ w3T, int K)
{
    int idx = blockIdx.x * 256 + threadIdx.x;
    int tot1 = K * H;
    if (idx < tot1) {
        int c = idx / K, k = idx - c * K;
        wInT[idx] = (_Float16)w_in[(size_t)k * H + c];
    } else {
        int i2 = idx - tot1;
        if (i2 < 3 * H * H) {
            int m = i2 / (H * H), r2 = i2 - m * (H * H);
            int c = r2 >> 7, k = r2 & 127;
            const float* s = (m == 0) ? w_root : (w_rel + (size_t)(m - 1) * H * H);
            w3T[i2] = (_Float16)s[(size_t)k * H + c];
        }
    }
}

__device__ __forceinline__ f16x8 cvt8(float4 v0, float4 v1) {
    f16x8 t;
    t[0] = (_Float16)v0.x; t[1] = (_Float16)v0.y; t[2] = (_Float16)v0.z; t[3] = (_Float16)v0.w;
    t[4] = (_Float16)v1.x; t[5] = (_Float16)v1.y; t[6] = (_Float16)v1.z; t[7] = (_Float16)v1.w;
    return t;
}

// ---------------- big GEMM, K-split, barrier-free K-loop -------------------------
// P[khalf] = A[:, khalf*KH : +KH] @ W-half  (fp32 partials). B-half (128 x 384
// f16 = 100 KB) lives in LDS, loaded once; ONE barrier total. 1024 thr = 16
// waves; wave = 16 rows x 128 cols. K-loop: independent A-loads + ds_read +
// MFMA, no barriers -> wave stalls desynchronize, CU issue stays continuous.
__global__ __launch_bounds__(1024, 4) void gemm_big(const float* __restrict__ A,
    const _Float16* __restrict__ WT, float* __restrict__ P,
    int M, int K, size_t NH)
{
    __shared__ _Float16 Bsh[128 * BSTRIDE];

    const int khalf = blockIdx.x & 1;
    const int rt    = blockIdx.x >> 1;
    const int KH    = K >> 1;                  // 384
    const int tid   = threadIdx.x;

    // stage B-half into LDS (once)
    {
        const int col = tid >> 3;
        const int seg = tid & 7;
        const _Float16* srcp = WT + (size_t)col * K + khalf * KH + seg * 8;
        _Float16* dstp = &Bsh[col * BSTRIDE + seg * 8];
        for (int k = 0; k < KH; k += 64)
            *(f16x8*)(dstp + k) = *(const f16x8*)(srcp + k);
    }
    __syncthreads();

    const int w   = tid >> 6;                  // 0..15: 16-row subtile
    const int l   = tid & 63;
    const int l15 = l & 15;
    const int q   = l >> 4;

    int arow = rt * 256 + w * 16 + l15;
    if (arow >= M) arow = M - 1;               // clamp loads; stores predicated
    const float* ap = A + (size_t)arow * K + khalf * KH + q * 8;

    f32x4 acc[8];
    const f32x4 z4 = {0.f, 0.f, 0.f, 0.f};
#pragma unroll
    for (int j = 0; j < 8; j++) acc[j] = z4;

    const int chunks = KH >> 5;                // 12
    float4 a0 = *(const float4*)(ap);
    float4 a1 = *(const float4*)(ap + 4);
#pragma unroll 2
    for (int c = 0; c < chunks; c++) {
        float4 n0, n1;
        if (c + 1 < chunks) {                  // independent next-chunk loads
            n0 = *(const float4*)(ap + (c + 1) * 32);
            n1 = *(const float4*)(ap + (c + 1) * 32 + 4);
        }
        f16x8 af = cvt8(a0, a1);
        const _Float16* bbase = &Bsh[l15 * BSTRIDE + c * 32 + q * 8];
#pragma unroll
        for (int j = 0; j < 8; j++) {
            f16x8 bf = *(const f16x8*)(bbase + j * 16 * BSTRIDE);
            acc[j] = __builtin_amdgcn_mfma_f32_16x16x32_f16(af, bf, acc[j], 0, 0, 0);
        }
        a0 = n0; a1 = n1;
    }

    // store fp32 partials (no bias/activation here — reduce kernel applies them)
    float* Pb = P + (size_t)khalf * NH;
#pragma unroll
    for (int j = 0; j < 8; j++) {
        int col = j * 16 + l15;
#pragma unroll
        for (int rg = 0; rg < 4; rg++) {
            int row = rt * 256 + w * 16 + q * 4 + rg;
            if (row < M) Pb[(size_t)row * H + col] = acc[j][rg];
        }
    }
}

// ---------------- reduce partials: x0 = fp16(leakyrelu(P0 + P1 + b)) -------------
__global__ __launch_bounds__(256) void reduce_x(const float* __restrict__ P,
    const float* __restrict__ b, _Float16* __restrict__ x0, int total8, size_t NH)
{
    int i = blockIdx.x * 256 + threadIdx.x;
    if (i >= total8) return;
    size_t off = (size_t)i * 8;
    float4 p00 = *(const float4*)(P + off);
    float4 p01 = *(const float4*)(P + off + 4);
    float4 p10 = *(const float4*)(P + NH + off);
    float4 p11 = *(const float4*)(P + NH + off + 4);
    int colb = (int)(off & (H - 1));
    float4 b0 = *(const float4*)(b + colb);
    float4 b1 = *(const float4*)(b + colb + 4);
    float v[8] = {p00.x + p10.x + b0.x, p00.y + p10.y + b0.y,
                  p00.z + p10.z + b0.z, p00.w + p10.w + b0.w,
                  p01.x + p11.x + b1.x, p01.y + p11.y + b1.y,
                  p01.z + p11.z + b1.z, p01.w + p11.w + b1.w};
    f16x8 o;
#pragma unroll
    for (int k = 0; k < 8; k++) {
        float t = v[k];
        t = (t >= 0.f) ? t : 0.01f * t;
        o[k] = (_Float16)t;
    }
    *(f16x8*)&x0[off] = o;
}

// ---------------- fused per-layer GEMM: B3 in regs, x software-pipelined ----------
__global__ __launch_bounds__(512) void gemm3(const _Float16* __restrict__ X16,
    const _Float16* __restrict__ W3, const float* __restrict__ bias,
    float* __restrict__ Y, _Float16* __restrict__ Hh, int M, int mtiles,
    size_t NH)
{
    const int w   = threadIdx.x >> 6;
    const int l   = threadIdx.x & 63;
    const int l15 = l & 15;
    const int q   = l >> 4;
    const int col = w * 16 + l15;

    f16x8 bf[3][4];
#pragma unroll
    for (int m = 0; m < 3; m++) {
        const _Float16* wpp = W3 + (size_t)m * H * H + (size_t)col * H + q * 8;
#pragma unroll
        for (int c = 0; c < 4; c++) bf[m][c] = *(const f16x8*)(wpp + c * 32);
    }
    const float bj = bias[col];

    int t = blockIdx.x;
    if (t >= mtiles) return;
    f16x8 xf[4];
    {
        const _Float16* xp = X16 + ((size_t)t * 16 + l15) * H + q * 8;
#pragma unroll
        for (int c = 0; c < 4; c++) xf[c] = *(const f16x8*)(xp + c * 32);
    }

    const f32x4 z4 = {0.f, 0.f, 0.f, 0.f};
    while (true) {
        int tn = t + gridDim.x;
        bool more = tn < mtiles;
        f16x8 xnf[4];
        if (more) {
            const _Float16* xp = X16 + ((size_t)tn * 16 + l15) * H + q * 8;
#pragma unroll
            for (int c = 0; c < 4; c++) xnf[c] = *(const f16x8*)(xp + c * 32);
        }

        f32x4 a0 = z4, a1 = z4, a2 = z4;
#pragma unroll
        for (int c = 0; c < 4; c++) {
            a0 = __builtin_amdgcn_mfma_f32_16x16x32_f16(xf[c], bf[0][c], a0, 0, 0, 0);
            a1 = __builtin_amdgcn_mfma_f32_16x16x32_f16(xf[c], bf[1][c], a1, 0, 0, 0);
            a2 = __builtin_amdgcn_mfma_f32_16x16x32_f16(xf[c], bf[2][c], a2, 0, 0, 0);
        }

#pragma unroll
        for (int rg = 0; rg < 4; rg++) {
            int row = t * 16 + q * 4 + rg;
            if (row < M) {
                Y [(size_t)row * H + col]      = a0[rg] + bj;
                Hh[(size_t)row * H + col]      = (_Float16)a1[rg];
                Hh[NH + (size_t)row * H + col] = (_Float16)a2[rg];
            }
        }
        if (!more) break;
        t = tn;
#pragma unroll
        for (int c = 0; c < 4; c++) xf[c] = xnf[c];
    }
}

// ---------------- mean-aggregate gather -------------------------------------------
// xn[dst] = fp16( y[dst] + sum_r mean(h_r[src]) ). One wave per dst row.
// Per-lane DIRECT elist loads (broadcast within slot group); NO shfl in
// divergent flow (ds_bpermute reads 0 from inactive lanes — learned round 6).
__global__ __launch_bounds__(256) void gather_mean(const float* __restrict__ Y,
    const _Float16* __restrict__ h, const int* __restrict__ elist,
    const int* __restrict__ cnt, _Float16* __restrict__ xn, int N, size_t NH)
{
    int wv = blockIdx.x * 4 + (threadIdx.x >> 6);
    int l  = threadIdx.x & 63;
    if (wv >= N) return;

    int d0r = cnt[wv], d1r = cnt[N + wv];
    int d0 = d0r < CAP ? d0r : CAP;
    int d1 = d1r < CAP ? d1r : CAP;
    float inv0 = d0r > 0 ? 1.f / (float)d0r : 0.f;
    float inv1 = d1r > 0 ? 1.f / (float)d1r : 0.f;
    const int* l0 = elist + (size_t)wv * CAP;
    const int* l1 = elist + ((size_t)N + wv) * CAP;
    const int tot = d0 + d1;

    const int eo = l >> 4;          // edge slot 0..3
    const int c8 = (l & 15) * 8;    // 8-col group

    float acc[8];
#pragma unroll
    for (int j = 0; j < 8; j++) acc[j] = 0.f;

    for (int p = eo; p < tot; p += 8) {
        int pb = p + 4;
        bool fA = p < d0;
        int   sA  = fA ? l0[p] : l1[p - d0];
        float scA = fA ? inv0 : inv1;
        size_t hA = fA ? (size_t)0 : NH;
        f16x8 vA  = *(const f16x8*)&h[hA + (size_t)sA * H + c8];
        if (pb < tot) {
            bool fB = pb < d0;
            int   sB  = fB ? l0[pb] : l1[pb - d0];
            float scB = fB ? inv0 : inv1;
            size_t hB = fB ? (size_t)0 : NH;
            f16x8 vB  = *(const f16x8*)&h[hB + (size_t)sB * H + c8];
#pragma unroll
            for (int j = 0; j < 8; j++) acc[j] += scA * (float)vA[j] + scB * (float)vB[j];
        } else {
#pragma unroll
            for (int j = 0; j < 8; j++) acc[j] += scA * (float)vA[j];
        }
    }

    // convergent full-wave reduction across the 4 edge slots
#pragma unroll
    for (int j = 0; j < 8; j++) {
        acc[j] += __shfl_xor(acc[j], 16);
        acc[j] += __shfl_xor(acc[j], 32);
    }

    if (eo == 0) {
        float4 y0 = *(const float4*)&Y[(size_t)wv * H + c8];
        float4 y1 = *(const float4*)&Y[(size_t)wv * H + c8 + 4];
        f16x8 o;
        o[0] = (_Float16)(acc[0] + y0.x); o[1] = (_Float16)(acc[1] + y0.y);
        o[2] = (_Float16)(acc[2] + y0.z); o[3] = (_Float16)(acc[3] + y0.w);
        o[4] = (_Float16)(acc[4] + y1.x); o[5] = (_Float16)(acc[5] + y1.y);
        o[6] = (_Float16)(acc[6] + y1.z); o[7] = (_Float16)(acc[7] + y1.w);
        *(f16x8*)&xn[(size_t)wv * H + c8] = o;
    }
}

// ---------------- final projection: out[N,OUT] = X[N,128] @ Wo[128,OUT] + bo ------
__global__ __launch_bounds__(256) void out_gemm(const _Float16* __restrict__ X16,
    const float* __restrict__ Wo, const float* __restrict__ bo,
    float* __restrict__ out, int N, int OUT)
{
    int row = blockIdx.x * 4 + (threadIdx.x >> 6);
    int lane = threadIdx.x & 63;
    if (row >= N) return;
    float a0 = (float)X16[(size_t)row * H + lane];
    float a1 = (float)X16[(size_t)row * H + 64 + lane];
    for (int c = 0; c < OUT; c++) {
        float p = a0 * Wo[lane * OUT + c] + a1 * Wo[(64 + lane) * OUT + c];
        for (int off = 32; off > 0; off >>= 1) p += __shfl_down(p, off);
        if (lane == 0) out[(size_t)row * OUT + c] = p + bo[c];
    }
}

extern "C" void kernel_launch(void* const* d_in, const int* in_sizes, int n_in,
                              void* d_out, int out_size, void* d_ws, size_t ws_size,
                              hipStream_t stream) {
    const float* feature = (const float*)d_in[0];
    const int*   ei      = (const int*)d_in[1];   // [2,E]: src then dst
    const int*   et      = (const int*)d_in[2];   // [E]
    const float* w_in    = (const float*)d_in[3];
    const float* b_in    = (const float*)d_in[4];
    const float* w_rel   = (const float*)d_in[5];
    const float* w_root  = (const float*)d_in[6];
    const float* b_conv  = (const float*)d_in[7];
    const float* w_out   = (const float*)d_in[8];
    const float* b_out   = (const float*)d_in[9];

    const int HH   = in_sizes[4];                 // 128
    const int D_IN = in_sizes[3] / HH;            // 768
    const int N    = in_sizes[0] / D_IN;          // 50000
    const int E    = in_sizes[1] / 2;             // 600000
    const int R    = in_sizes[5] / (HH * HH);     // 2 (layout assumes 2)
    const int OUT  = in_sizes[9];                 // 3

    const size_t NH = (size_t)N * H;

    // workspace layout (16B-aligned segments)
    char* base = (char*)d_ws;
    _Float16* wInT = (_Float16*)base;                              // 128*K
    _Float16* w3T  = wInT + (size_t)D_IN * HH;                     // 3*128*128
    _Float16* x0   = w3T + (size_t)3 * HH * HH;                    // N*H fp16
    _Float16* x1   = x0 + NH;                                      // N*H fp16
    _Float16* h    = x1 + NH;                                      // R*N*H fp16
    float* y       = (float*)(h + (size_t)R * NH);                 // N*H fp32
    float* P       = y + NH;                                       // 2*N*H fp32 partials
    int* cnt       = (int*)(P + 2 * NH);                           // R*N
    int* elist     = cnt + (size_t)R * N;                          // R*N*CAP

    hipMemsetAsync(cnt, 0, sizeof(int) * (size_t)R * N, stream);
    prep_w<<<(D_IN * HH + 3 * HH * HH + 255) / 256, 256, 0, stream>>>(
        w_in, w_root, w_rel, wInT, w3T, D_IN);
    hist_fill<<<(E + 255) / 256, 256, 0, stream>>>(ei, ei + E, et, cnt, elist, E, N);

    // P[k] = feature[:, k-half] @ w_in-half ; then x0 = fp16(leaky(P0+P1+b))
    const int rgroups = (N + 255) / 256;
    gemm_big<<<2 * rgroups, 1024, 0, stream>>>(feature, wInT, P, N, D_IN, NH);
    reduce_x<<<(N * (H / 8) + 255) / 256, 256, 0, stream>>>(P, b_in, x0, N * (H / 8), NH);

    const int mtiles = (N + 15) / 16;             // 3125 exact for N=50000
    _Float16* xc = x0;
    _Float16* xo = x1;
    for (int layer = 0; layer < 2; layer++) {
        gemm3<<<1024, 512, 0, stream>>>(xc, w3T, b_conv, y, h, N, mtiles, NH);
        gather_mean<<<(N + 3) / 4, 256, 0, stream>>>(y, h, elist, cnt, xo, N, NH);
        _Float16* t = xc; xc = xo; xo = t;
    }

    out_gemm<<<(N + 3) / 4, 256, 0, stream>>>(xc, w_out, b_out, (float*)d_out, N, OUT);
}